// Round 1
// baseline (502.855 us; speedup 1.0000x reference)
//
#include <hip/hip_runtime.h>
#include <hip/hip_bf16.h>
#include <stdint.h>

typedef unsigned short ushort_t;
typedef __bf16 bf16x8 __attribute__((ext_vector_type(8)));
typedef float f32x4 __attribute__((ext_vector_type(4)));

// ---------- helpers ----------
__device__ __forceinline__ ushort_t f2bf(float f) {
    union { float f; unsigned u; } v; v.f = f;
    unsigned u = v.u;
    unsigned r = u + 0x7fffu + ((u >> 16) & 1u);   // RNE
    return (ushort_t)(r >> 16);
}
__device__ __forceinline__ float bf2f(ushort_t h) {
    union { unsigned u; float f; } v; v.u = ((unsigned)h) << 16;
    return v.f;
}
__device__ __forceinline__ uint4 pack8(float4 a, float4 b) {
    uint4 r;
    r.x = ((unsigned)f2bf(a.y) << 16) | f2bf(a.x);
    r.y = ((unsigned)f2bf(a.w) << 16) | f2bf(a.z);
    r.z = ((unsigned)f2bf(b.y) << 16) | f2bf(b.x);
    r.w = ((unsigned)f2bf(b.w) << 16) | f2bf(b.z);
    return r;
}

#define GLDS16(gsrc, ldst)                                                    \
    __builtin_amdgcn_global_load_lds(                                         \
        (const __attribute__((address_space(1))) void*)(gsrc),                \
        (__attribute__((address_space(3))) void*)(ldst), 16, 0, 0)

// ---------- prep: W1 -> padded bf16 [512][800], W2 -> bf16, stats=0 ----------
__global__ __launch_bounds__(256) void prep_kernel(
    const float* __restrict__ W1, const float* __restrict__ W2,
    ushort_t* __restrict__ W1p, ushort_t* __restrict__ W2b,
    float* __restrict__ stats)
{
    int idx = blockIdx.x * 256 + threadIdx.x;
    if (idx < 512 * 800) {
        int n = idx / 800, k = idx - n * 800;
        W1p[idx] = (k < 784) ? f2bf(W1[n * 784 + k]) : (ushort_t)0;
    }
    if (idx < 128 * 512) W2b[idx] = f2bf(W2[idx]);
    if (idx == 0) stats[0] = 0.0f;
}

// ---------- gemm1f: h1 = relu(X @ W1p^T + b1) ----------
// 128x128 tile. Cross-iteration double-buffered 2-phase schedule: one 32-wide
// K panel per step, 25 steps. Per step: issue next-step staging FIRST
// (B via global_load_lds into buf^1, A converted from regs prefetched two
// steps ahead and ds_written into buf^1, then issue A fp32 loads for t+2),
// THEN ds_read+MFMA the current buffer, THEN the single barrier. The
// vmcnt(0) drain at the barrier lands after the compute phase, so load
// latency hides under the 16 MFMAs instead of serializing before them.
// grid 2176 = 8 XCDs x 68 tile_m x 4 tile_n (same-tile_m blocks share an XCD
// so fp32 A rows are fetched from HBM once per XCD).
__global__ __launch_bounds__(256) void gemm1f_kernel(
    const float* __restrict__ x, const float* __restrict__ xu,
    const ushort_t* __restrict__ W1p, const float* __restrict__ b1,
    ushort_t* __restrict__ h1)
{
    __shared__ ushort_t As[2][128 * 32];   // 2 x 8 KB
    __shared__ ushort_t Bs[2][128 * 32];   // 2 x 8 KB  (32 KB total)

    const int b = blockIdx.x;
    const int xcd = b & 7, s = b >> 3;
    const int tile_n = s & 3;
    const int tile_m = xcd * 68 + (s >> 2);

    const int tid = threadIdx.x;
    const int w = tid >> 6, lane = tid & 63;
    const int wm = w >> 1, wn = w & 1;
    const int quad = lane >> 4, lc = lane & 15;
    const int row_in = lane >> 2;
    const int koff = (lane & 3) * 8;

    // A convert-staging geometry: 2 threads/row, 16 floats each
    const int arow = tid >> 1;
    const int akoff = (tid & 1) * 16;
    const int grow = tile_m * 128 + arow;
    const float* asrc = (grow < 65536) ? (x + (size_t)grow * 784)
                                       : (xu + (size_t)(grow - 65536) * 784);

    // B source rows for this thread's two GLDS chunks
    const ushort_t* bsrc0 =
        W1p + (size_t)(tile_n * 128 + (w * 2 + 0) * 16 + row_in) * 800 + koff;
    const ushort_t* bsrc1 =
        W1p + (size_t)(tile_n * 128 + (w * 2 + 1) * 16 + row_in) * 800 + koff;

    f32x4 acc[4][4];
#pragma unroll
    for (int i = 0; i < 4; i++)
#pragma unroll
        for (int j = 0; j < 4; j++)
#pragma unroll
            for (int r = 0; r < 4; r++) acc[i][j][r] = 0.0f;

    float4 pa0, pa1, pa2, pa3;   // A fp32 prefetch for step t+1

    // ---- prologue: stage step 0 directly, prefetch A for step 1 ----
    GLDS16(bsrc0, &Bs[0][(w * 2 + 0) * 512]);
    GLDS16(bsrc1, &Bs[0][(w * 2 + 1) * 512]);
    {
        const float4* q = (const float4*)(asrc + akoff);   // k<=31 always valid
        float4 a0 = q[0], a1 = q[1], a2 = q[2], a3 = q[3];
        *(uint4*)&As[0][arow * 32 + akoff]     = pack8(a0, a1);
        *(uint4*)&As[0][arow * 32 + akoff + 8] = pack8(a2, a3);
    }
    {
        const float4* q = (const float4*)(asrc + 32 + akoff);
        pa0 = q[0]; pa1 = q[1]; pa2 = q[2]; pa3 = q[3];
    }
    __syncthreads();

    for (int t = 0; t < 25; ++t) {
        const int cur = t & 1;
        if (t < 24) {
            ushort_t* Asn = &As[cur ^ 1][0];
            ushort_t* Bsn = &Bs[cur ^ 1][0];
            const int kb = (t + 1) * 32;
            // B for t+1 (async, drained by this step's barrier after compute)
            GLDS16(bsrc0 + kb, &Bsn[(w * 2 + 0) * 512]);
            GLDS16(bsrc1 + kb, &Bsn[(w * 2 + 1) * 512]);
            // A for t+1 from regs prefetched at t-1
            uint4 lo, hi;
            if (kb + akoff <= 768) {
                lo = pack8(pa0, pa1);
                hi = pack8(pa2, pa3);
            } else {
                lo = make_uint4(0, 0, 0, 0);
                hi = make_uint4(0, 0, 0, 0);
            }
            *(uint4*)&Asn[arow * 32 + akoff]     = lo;
            *(uint4*)&Asn[arow * 32 + akoff + 8] = hi;
            // A fp32 prefetch for t+2 (latency covered by this compute + next)
            const int kn = (t + 2) * 32 + akoff;
            if (t < 23 && kn <= 768) {
                const float4* q = (const float4*)(asrc + kn);
                pa0 = q[0]; pa1 = q[1]; pa2 = q[2]; pa3 = q[3];
            }
        }
        // ---- compute current buffer ----
        {
            bf16x8 af[4], bfr[4];
#pragma unroll
            for (int i = 0; i < 4; i++)
                af[i] = *(const bf16x8*)&As[cur][(wm * 64 + i * 16 + lc) * 32 + quad * 8];
#pragma unroll
            for (int j = 0; j < 4; j++)
                bfr[j] = *(const bf16x8*)&Bs[cur][(wn * 64 + j * 16 + lc) * 32 + quad * 8];
#pragma unroll
            for (int i = 0; i < 4; i++)
#pragma unroll
                for (int j = 0; j < 4; j++)
                    acc[i][j] = __builtin_amdgcn_mfma_f32_16x16x32_bf16(
                        af[i], bfr[j], acc[i][j], 0, 0, 0);
        }
        if (t < 24) __syncthreads();
    }

    // epilogue: relu(acc + b1) -> bf16
    float bias[4];
#pragma unroll
    for (int j = 0; j < 4; j++)
        bias[j] = b1[tile_n * 128 + wn * 64 + j * 16 + lc];
#pragma unroll
    for (int i = 0; i < 4; i++) {
        int gr0 = tile_m * 128 + wm * 64 + i * 16 + quad * 4;
#pragma unroll
        for (int j = 0; j < 4; j++) {
            int gc = tile_n * 128 + wn * 64 + j * 16 + lc;
#pragma unroll
            for (int r = 0; r < 4; r++) {
                float v = acc[i][j][r] + bias[j];
                v = fmaxf(v, 0.0f);
                h1[(size_t)(gr0 + r) * 512 + gc] = f2bf(v);
            }
        }
    }
}

// ---------- gemm23: h2 = relu(h1 @ W2b^T + b2) fused with fc3 + losses ----------
// 64x128 tile (full N), K=512 in 16 single-panel double-buffered steps with
// the same issue-next / compute-current / barrier schedule. h2 never leaves
// LDS. Labeled rows -> BCE partial (atomicAdd); unlabeled rows -> logits_u.
__global__ __launch_bounds__(256) void gemm23_kernel(
    const ushort_t* __restrict__ h1, const ushort_t* __restrict__ W2b,
    const float* __restrict__ b2, const int* __restrict__ y,
    const float* __restrict__ W3, const float* __restrict__ b3,
    float* __restrict__ stats, float* __restrict__ logits_u)
{
    __shared__ ushort_t As[2][64 * 32];    // 2 x 4 KB
    __shared__ ushort_t Bs[2][128 * 32];   // 2 x 8 KB (reused as h2 tile later)
    __shared__ float W3s[1280];
    __shared__ float b3s[10];
    __shared__ float red[4];

    const int tid = threadIdx.x;
    const int w = tid >> 6, lane = tid & 63;
    const int wm = w >> 1, wn = w & 1;
    const int quad = lane >> 4, lc = lane & 15;
    const int row_in = lane >> 2;
    const int koff = (lane & 3) * 8;
    const int tile_m = blockIdx.x;

    for (int i = tid; i < 1280; i += 256) W3s[i] = W3[i];
    if (tid < 10) b3s[tid] = b3[tid];

    const ushort_t* asrc =
        h1 + (size_t)(tile_m * 64 + w * 16 + row_in) * 512 + koff;
    const ushort_t* bsrc0 =
        W2b + (size_t)((w * 2 + 0) * 16 + row_in) * 512 + koff;
    const ushort_t* bsrc1 =
        W2b + (size_t)((w * 2 + 1) * 16 + row_in) * 512 + koff;

    f32x4 acc[2][4];
#pragma unroll
    for (int i = 0; i < 2; i++)
#pragma unroll
        for (int j = 0; j < 4; j++)
#pragma unroll
            for (int r = 0; r < 4; r++) acc[i][j][r] = 0.0f;

    // prologue: stage step 0
    GLDS16(asrc,  &As[0][w * 512]);
    GLDS16(bsrc0, &Bs[0][(w * 2 + 0) * 512]);
    GLDS16(bsrc1, &Bs[0][(w * 2 + 1) * 512]);
    __syncthreads();

    for (int t = 0; t < 16; ++t) {
        const int cur = t & 1;
        if (t < 15) {
            const int kb = (t + 1) * 32;
            GLDS16(asrc + kb,  &As[cur ^ 1][w * 512]);
            GLDS16(bsrc0 + kb, &Bs[cur ^ 1][(w * 2 + 0) * 512]);
            GLDS16(bsrc1 + kb, &Bs[cur ^ 1][(w * 2 + 1) * 512]);
        }
        {
            bf16x8 af[2], bfr[4];
#pragma unroll
            for (int i = 0; i < 2; i++)
                af[i] = *(const bf16x8*)&As[cur][(wm * 32 + i * 16 + lc) * 32 + quad * 8];
#pragma unroll
            for (int j = 0; j < 4; j++)
                bfr[j] = *(const bf16x8*)&Bs[cur][(wn * 64 + j * 16 + lc) * 32 + quad * 8];
#pragma unroll
            for (int i = 0; i < 2; i++)
#pragma unroll
                for (int j = 0; j < 4; j++)
                    acc[i][j] = __builtin_amdgcn_mfma_f32_16x16x32_bf16(
                        af[i], bfr[j], acc[i][j], 0, 0, 0);
        }
        __syncthreads();   // also separates last compute from h2 staging
    }

    // stage h2 tile (bias+relu, bf16) into LDS over Bs (done reading it)
    ushort_t* h2s = &Bs[0][0];   // 64*128 ushort = 16 KB
    float bias[4];
#pragma unroll
    for (int j = 0; j < 4; j++) bias[j] = b2[wn * 64 + j * 16 + lc];
#pragma unroll
    for (int i = 0; i < 2; i++) {
        int row0 = wm * 32 + i * 16 + quad * 4;
#pragma unroll
        for (int j = 0; j < 4; j++) {
            int col = wn * 64 + j * 16 + lc;
#pragma unroll
            for (int r = 0; r < 4; r++) {
                float v = fmaxf(acc[i][j][r] + bias[j], 0.0f);
                h2s[(row0 + r) * 128 + col] = f2bf(v);
            }
        }
    }
    __syncthreads();

    // fc3 + loss
    const size_t row0g = (size_t)tile_m * 64;
    float bce_part = 0.0f;
    for (int o = tid; o < 640; o += 256) {
        int r = o / 10, c = o - r * 10;
        size_t grw = row0g + r;
        float a = b3s[c];
        const ushort_t* hr = &h2s[r * 128];
        const float* wr = &W3s[c * 128];
#pragma unroll 8
        for (int k = 0; k < 128; k++) a += bf2f(hr[k]) * wr[k];
        if (grw < 65536) {
            float t = (y[grw] == c) ? 1.0f : 0.0f;
            bce_part += fmaxf(a, 0.0f) - a * t + log1pf(__expf(-fabsf(a)));
        } else {
            logits_u[(grw - 65536) * 10 + c] = a;
        }
    }
#pragma unroll
    for (int s = 32; s > 0; s >>= 1) bce_part += __shfl_down(bce_part, s, 64);
    if ((tid & 63) == 0) red[tid >> 6] = bce_part;
    __syncthreads();
    if (tid == 0) atomicAdd(stats, red[0] + red[1] + red[2] + red[3]);
}

// ---------- finisher: semantic loss + output write ----------
// log_s[c] = S[c] + logsumexp_i(o_i[c]),  S[c] = sum_i logsigmoid(-o_i[c])
__global__ __launch_bounds__(640) void finisher_kernel(
    const float* __restrict__ logits_u, const float* __restrict__ stats,
    float* __restrict__ out)
{
    __shared__ float Rs[64][10];
    __shared__ float Rm[64][10];
    __shared__ float Scol[10], Mcol[10];

    const int tid = threadIdx.x;
    const int g = tid / 10, c = tid - g * 10;   // 64 groups x 10 cols
    float s = 0.0f, m = -1e30f;
    for (int i = g; i < 4096; i += 64) {
        float o = logits_u[i * 10 + c];
        s += fminf(-o, 0.0f) - log1pf(__expf(-fabsf(o)));
        m = fmaxf(m, o);
    }
    Rs[g][c] = s;
    Rm[g][c] = m;
    __syncthreads();
    if (tid < 10) {
        float ss = 0.0f, mm = -1e30f;
        for (int gg = 0; gg < 64; gg++) {
            ss += Rs[gg][tid];
            mm = fmaxf(mm, Rm[gg][tid]);
        }
        Scol[tid] = ss;
        Mcol[tid] = mm;
    }
    __syncthreads();
    float e = 0.0f;
    float mm = Mcol[c];
    for (int i = g; i < 4096; i += 64)
        e += __expf(logits_u[i * 10 + c] - mm);
    Rs[g][c] = e;
    __syncthreads();
    if (tid == 0) {
        float sl = 0.0f;
        for (int cc = 0; cc < 10; cc++) {
            float ee = 0.0f;
            for (int gg = 0; gg < 64; gg++) ee += Rs[gg][cc];
            sl += -(Scol[cc] + Mcol[cc] + __logf(ee));
        }
        sl *= 0.1f;
        out[0] = stats[0] * (1.0f / (65536.0f * 10.0f));
        out[1] = sl;
    }
}

// ---------- launch ----------
extern "C" void kernel_launch(void* const* d_in, const int* in_sizes, int n_in,
                              void* d_out, int out_size, void* d_ws,
                              size_t ws_size, hipStream_t stream)
{
    const float* x  = (const float*)d_in[0];   // 65536x784
    const int*   y  = (const int*)d_in[1];     // 65536
    const float* xu = (const float*)d_in[2];   // 4096x784
    const float* W1 = (const float*)d_in[3];   // 512x784
    const float* b1 = (const float*)d_in[4];   // 512
    const float* W2 = (const float*)d_in[5];   // 128x512
    const float* b2 = (const float*)d_in[6];   // 128
    const float* W3 = (const float*)d_in[7];   // 10x128
    const float* b3 = (const float*)d_in[8];   // 10
    float* out = (float*)d_out;

    char* ws = (char*)d_ws;
    // layout (bytes), total 72.4 MB:
    ushort_t* W1p      = (ushort_t*)(ws + 0);          // 819200
    ushort_t* W2b      = (ushort_t*)(ws + 819200);     // 131072 -> 950272
    float*    stats    = (float*)(ws + 950272);        // 256    -> 950528
    float*    logits_u = (float*)(ws + 950528);        // 163840 -> 1114368
    ushort_t* h1       = (ushort_t*)(ws + 1114368);    // 71303168 -> 72417536

    prep_kernel<<<1600, 256, 0, stream>>>(W1, W2, W1p, W2b, stats);
    gemm1f_kernel<<<2176, 256, 0, stream>>>(x, xu, W1p, b1, h1);
    gemm23_kernel<<<1088, 256, 0, stream>>>(h1, W2b, b2, y, W3, b3, stats,
                                            logits_u);
    finisher_kernel<<<1, 640, 0, stream>>>(logits_u, stats, out);
    (void)in_sizes; (void)n_in; (void)out_size; (void)ws_size;
}